// Round 16
// baseline (204.568 us; speedup 1.0000x reference)
//
#include <hip/hip_runtime.h>

#define N_TOK 8192
#define DIN   1024
#define DOUT  1024
#define NE    8

#define BM 256
#define BN 128
#define BK 64

typedef __attribute__((ext_vector_type(8))) short  short8;
typedef __attribute__((ext_vector_type(4))) float  f32x4;
typedef unsigned int u32;

__device__ __forceinline__ unsigned short f2bf(float f) {
  union { float f; unsigned int u; } v; v.f = f;
  unsigned int u = v.u;
  unsigned int r = (u + 0x7fffu + ((u >> 16) & 1u)) >> 16;
  return (unsigned short)r;
}

__device__ __forceinline__ float dot4(float4 a, float4 b) {
  return a.x*b.x + a.y*b.y + a.z*b.z + a.w*b.w;
}

// async global -> LDS, 16B per lane; LDS dest = wave-uniform base + lane*16.
__device__ __forceinline__ void gload16(const unsigned short* g, unsigned short* l) {
  __builtin_amdgcn_global_load_lds(
      (const __attribute__((address_space(1))) u32*)g,
      (__attribute__((address_space(3))) u32*)l, 16, 0, 0);
}

__device__ __forceinline__ void memfence_compiler() {
  asm volatile("" ::: "memory");
}

// ---------------- gates + x->bf16 conversion (reads x once) ----------------
__global__ __launch_bounds__(256) void gates_cvtx(
    const float* __restrict__ x, const float* __restrict__ gw,
    const float* __restrict__ gb, float* __restrict__ gates,
    unsigned short* __restrict__ xb) {
  const int lane = threadIdx.x & 63;
  const int wave = threadIdx.x >> 6;
  const int n = blockIdx.x * 4 + wave;

  const float4* xr = reinterpret_cast<const float4*>(x + (size_t)n * DIN) + lane * 4;
  float4 xv0 = xr[0], xv1 = xr[1], xv2 = xr[2], xv3 = xr[3];

  short8 v0, v1;
  v0[0] = (short)f2bf(xv0.x); v0[1] = (short)f2bf(xv0.y);
  v0[2] = (short)f2bf(xv0.z); v0[3] = (short)f2bf(xv0.w);
  v0[4] = (short)f2bf(xv1.x); v0[5] = (short)f2bf(xv1.y);
  v0[6] = (short)f2bf(xv1.z); v0[7] = (short)f2bf(xv1.w);
  v1[0] = (short)f2bf(xv2.x); v1[1] = (short)f2bf(xv2.y);
  v1[2] = (short)f2bf(xv2.z); v1[3] = (short)f2bf(xv2.w);
  v1[4] = (short)f2bf(xv3.x); v1[5] = (short)f2bf(xv3.y);
  v1[6] = (short)f2bf(xv3.z); v1[7] = (short)f2bf(xv3.w);
  unsigned short* xo = xb + (size_t)n * DIN + lane * 16;
  *reinterpret_cast<short8*>(xo) = v0;
  *reinterpret_cast<short8*>(xo + 8) = v1;

  float p[NE];
#pragma unroll
  for (int e = 0; e < NE; ++e) {
    const float4* wr = reinterpret_cast<const float4*>(gw + e * DIN) + lane * 4;
    float4 w0 = wr[0], w1 = wr[1], w2 = wr[2], w3 = wr[3];
    p[e] = dot4(xv0, w0) + dot4(xv1, w1) + dot4(xv2, w2) + dot4(xv3, w3);
  }
#pragma unroll
  for (int off = 1; off < 64; off <<= 1) {
#pragma unroll
    for (int e = 0; e < NE; ++e) p[e] += __shfl_xor(p[e], off, 64);
  }
  float mx = -1e30f;
#pragma unroll
  for (int e = 0; e < NE; ++e) { p[e] += gb[e]; mx = fmaxf(mx, p[e]); }
  float s = 0.f;
#pragma unroll
  for (int e = 0; e < NE; ++e) { p[e] = __expf(p[e] - mx); s += p[e]; }
  float inv = 1.0f / s;
  if (lane < NE) gates[(size_t)n * NE + lane] = p[lane] * inv;
}

// ---------------- W -> bf16 ----------------
__global__ __launch_bounds__(256) void cvt_w(
    const float* __restrict__ w, unsigned short* __restrict__ wb) {
  const size_t i = ((size_t)blockIdx.x * 256 + threadIdx.x) * 8;
  float4 a0 = *reinterpret_cast<const float4*>(w + i);
  float4 a1 = *reinterpret_cast<const float4*>(w + i + 4);
  short8 v;
  v[0] = (short)f2bf(a0.x); v[1] = (short)f2bf(a0.y);
  v[2] = (short)f2bf(a0.z); v[3] = (short)f2bf(a0.w);
  v[4] = (short)f2bf(a1.x); v[5] = (short)f2bf(a1.y);
  v[6] = (short)f2bf(a1.z); v[7] = (short)f2bf(a1.w);
  *reinterpret_cast<short8*>(wb + i) = v;
}

// ---------------- main GEMM v15: v10 + granular in-order lgkm waits.
// 256x128, 8 waves (4M x 2N), 64x64/wave, 3-deep LDS ring (144 KB),
// 1 barrier/K-tile, counted vmcnt(6). Read order b0,a0,b1,a1 (DS completes
// in-order per wave) -> MFMA quad mi of cluster 1 starts at lgkm(11-mi),
// cluster 2 at lgkm(3-mi): ds_read completion overlaps MFMA issue.
// Stage gloads issued at tile top (earlier HBM entry; vmcnt count same).
// Both-sides XOR swizzle (0 conflicts), Horner gate fold, XCD->bm-chunk map.
__global__ __launch_bounds__(512, 1) void moe_gemm_v15(
    const unsigned short* __restrict__ xb,   // [N_TOK][DIN] bf16
    const unsigned short* __restrict__ wb,   // [NE*DOUT][DIN] bf16
    const float* __restrict__ bias,          // [NE][DOUT]
    const float* __restrict__ gates,         // [N_TOK][NE]
    float* __restrict__ out) {               // [N_TOK][DOUT]
  __shared__ __align__(16) unsigned short As[3][BM * BK];  // 96 KB
  __shared__ __align__(16) unsigned short Bs[3][BN * BK];  // 48 KB

  const int tid = threadIdx.x;
  // XCD->bm-chunk map: xcd k owns bm in [4k,4k+4), all 8 bn (4MB set, L2-fit)
  const int d   = (int)blockIdx.x;
  const int xcd = d & 7;
  const int j   = d >> 3;              // 0..31
  const int bm  = xcd * 4 + (j & 3);   // 0..31
  const int bn  = j >> 2;              // 0..7

  const int lane = tid & 63;
  const int wv   = tid >> 6;       // 8 waves: 4 (M) x 2 (N)
  const int wm   = wv >> 1;        // 0..3
  const int wn   = wv & 1;         // 0..1
  const int lr   = lane & 15;
  const int g16  = lane >> 4;      // 0..3

  // staging: each instr covers 64 rows (8 rows/wave-slice); lane covers
  // row (.. + wv*8 + (lane>>3)), slot lane&7; pre-swizzled global col.
  const int sr8  = lane >> 3;
  const int scol = 8 * ((lane & 7) ^ (sr8 & 7));
  const unsigned short* a_src  = xb + (size_t)(bm * BM + wv * 8 + sr8) * DIN + scol;
  const unsigned short* b_src0 = wb + (size_t)(bn * BN + wv * 8 + sr8) * DIN + scol;

  const int rq = g16 * 4;
  const int cc = lane & 15;
  const int orow0 = bm * BM + wm * 64;

  // frag-read row offsets (elements)
  int rowA[4], rowB[4];
#pragma unroll
  for (int mi = 0; mi < 4; ++mi) rowA[mi] = (wm * 64 + mi * 16 + lr) * BK;
#pragma unroll
  for (int ni = 0; ni < 4; ++ni) rowB[ni] = (wn * 64 + ni * 16 + lr) * BK;
  const int sw0 = ((g16 ^ (lr & 7)) << 3);            // kh=0
  const int sw1 = (((4 + g16) ^ (lr & 7)) << 3);      // kh=1

  f32x4 acc[4][4];
#pragma unroll
  for (int i = 0; i < 4; ++i)
#pragma unroll
    for (int j2 = 0; j2 < 4; ++j2) acc[i][j2] = (f32x4){0.f, 0.f, 0.f, 0.f};

  float g_prev[16];
#pragma unroll
  for (int mi = 0; mi < 4; ++mi)
#pragma unroll
    for (int q = 0; q < 4; ++q)
      g_prev[mi * 4 + q] = gates[(size_t)(orow0 + mi * 16 + rq + q) * NE];

  // rotating ring pointers
  unsigned short *curA = &As[0][0], *nxtA = &As[1][0], *stgA = &As[2][0];
  unsigned short *curB = &Bs[0][0], *nxtB = &Bs[1][0], *stgB = &Bs[2][0];

  // prologue: stage t0 -> buf0, t1 -> buf1 (6+6 loads per thread)
#pragma unroll
  for (int i = 0; i < 4; ++i)
    gload16(a_src + (size_t)i * 64 * DIN, curA + (i * 64 + wv * 8) * BK);
#pragma unroll
  for (int j2 = 0; j2 < 2; ++j2)
    gload16(b_src0 + (size_t)j2 * 64 * DIN, curB + (j2 * 64 + wv * 8) * BK);
  {
    const unsigned short* ak = a_src + 1 * BK;          // t=1: e0,kk1
    const unsigned short* bk = b_src0 + 1 * BK;
#pragma unroll
    for (int i = 0; i < 4; ++i)
      gload16(ak + (size_t)i * 64 * DIN, nxtA + (i * 64 + wv * 8) * BK);
#pragma unroll
    for (int j2 = 0; j2 < 2; ++j2)
      gload16(bk + (size_t)j2 * 64 * DIN, nxtB + (j2 * 64 + wv * 8) * BK);
  }
  asm volatile("s_waitcnt vmcnt(6)" ::: "memory");   // t0 landed
  __builtin_amdgcn_s_barrier();
  memfence_compiler();

  for (int t = 0; t < 128; ++t) {
    const int e  = t >> 4;

    // ---- Horner gate boundary: acc *= g_{e-1}/g_e ----
    if ((t & 15) == 0 && e) {
#pragma unroll
      for (int mi = 0; mi < 4; ++mi)
#pragma unroll
        for (int q = 0; q < 4; ++q) {
          const int row = orow0 + mi * 16 + rq + q;
          const float gn = fmaxf(gates[(size_t)row * NE + e], 1e-37f);
          const float r = g_prev[mi * 4 + q] / gn;
          g_prev[mi * 4 + q] = gn;
#pragma unroll
          for (int ni = 0; ni < 4; ++ni) acc[mi][ni][q] *= r;
        }
    }

    // source for tile t+2 (wraps to dummy restage at tail)
    int tn = t + 2; if (tn >= 128) tn -= 128;
    const int en = tn >> 4;
    const int kn = tn & 15;
    const unsigned short* ak = a_src + kn * BK;
    const unsigned short* bk = b_src0 + (size_t)en * DOUT * DIN + kn * BK;

    // ---- stage tile t+2 into stg FIRST (6 gloads; vmcnt only) ----
    gload16(ak,                     stgA + (wv * 8) * BK);
    gload16(ak + (size_t)64 * DIN,  stgA + (64 + wv * 8) * BK);
    gload16(ak + (size_t)128 * DIN, stgA + (128 + wv * 8) * BK);
    gload16(ak + (size_t)192 * DIN, stgA + (192 + wv * 8) * BK);
    gload16(bk,                     stgB + (wv * 8) * BK);
    gload16(bk + (size_t)64 * DIN,  stgB + (64 + wv * 8) * BK);
    memfence_compiler();

    // ---- issue frag reads in order: b0, a0, b1, a1 (16 ds_read_b128) ----
    short8 af0[4], bf0[4], af1[4], bf1[4];
#pragma unroll
    for (int ni = 0; ni < 4; ++ni)
      bf0[ni] = *reinterpret_cast<const short8*>(&curB[rowB[ni] + sw0]);
#pragma unroll
    for (int mi = 0; mi < 4; ++mi)
      af0[mi] = *reinterpret_cast<const short8*>(&curA[rowA[mi] + sw0]);
#pragma unroll
    for (int ni = 0; ni < 4; ++ni)
      bf1[ni] = *reinterpret_cast<const short8*>(&curB[rowB[ni] + sw1]);
#pragma unroll
    for (int mi = 0; mi < 4; ++mi)
      af1[mi] = *reinterpret_cast<const short8*>(&curA[rowA[mi] + sw1]);
    memfence_compiler();

    // ---- cluster 1 (kh0): group mi ready at lgkm(11-mi) (in-order DS) ----
    __builtin_amdgcn_s_setprio(1);
    asm volatile("s_waitcnt lgkmcnt(11)" ::: "memory");
    __builtin_amdgcn_sched_barrier(0);
#pragma unroll
    for (int ni = 0; ni < 4; ++ni)
      acc[0][ni] = __builtin_amdgcn_mfma_f32_16x16x32_bf16(af0[0], bf0[ni], acc[0][ni], 0, 0, 0);
    asm volatile("s_waitcnt lgkmcnt(10)" ::: "memory");
    __builtin_amdgcn_sched_barrier(0);
#pragma unroll
    for (int ni = 0; ni < 4; ++ni)
      acc[1][ni] = __builtin_amdgcn_mfma_f32_16x16x32_bf16(af0[1], bf0[ni], acc[1][ni], 0, 0, 0);
    asm volatile("s_waitcnt lgkmcnt(9)" ::: "memory");
    __builtin_amdgcn_sched_barrier(0);
#pragma unroll
    for (int ni = 0; ni < 4; ++ni)
      acc[2][ni] = __builtin_amdgcn_mfma_f32_16x16x32_bf16(af0[2], bf0[ni], acc[2][ni], 0, 0, 0);
    asm volatile("s_waitcnt lgkmcnt(8)" ::: "memory");
    __builtin_amdgcn_sched_barrier(0);
#pragma unroll
    for (int ni = 0; ni < 4; ++ni)
      acc[3][ni] = __builtin_amdgcn_mfma_f32_16x16x32_bf16(af0[3], bf0[ni], acc[3][ni], 0, 0, 0);

    // ---- cluster 2 (kh1): group mi ready at lgkm(3-mi) ----
    asm volatile("s_waitcnt lgkmcnt(3)" ::: "memory");
    __builtin_amdgcn_sched_barrier(0);
#pragma unroll
    for (int ni = 0; ni < 4; ++ni)
      acc[0][ni] = __builtin_amdgcn_mfma_f32_16x16x32_bf16(af1[0], bf1[ni], acc[0][ni], 0, 0, 0);
    asm volatile("s_waitcnt lgkmcnt(2)" ::: "memory");
    __builtin_amdgcn_sched_barrier(0);
#pragma unroll
    for (int ni = 0; ni < 4; ++ni)
      acc[1][ni] = __builtin_amdgcn_mfma_f32_16x16x32_bf16(af1[1], bf1[ni], acc[1][ni], 0, 0, 0);
    asm volatile("s_waitcnt lgkmcnt(1)" ::: "memory");
    __builtin_amdgcn_sched_barrier(0);
#pragma unroll
    for (int ni = 0; ni < 4; ++ni)
      acc[2][ni] = __builtin_amdgcn_mfma_f32_16x16x32_bf16(af1[2], bf1[ni], acc[2][ni], 0, 0, 0);
    asm volatile("s_waitcnt lgkmcnt(0)" ::: "memory");
    __builtin_amdgcn_sched_barrier(0);
#pragma unroll
    for (int ni = 0; ni < 4; ++ni)
      acc[3][ni] = __builtin_amdgcn_mfma_f32_16x16x32_bf16(af1[3], bf1[ni], acc[3][ni], 0, 0, 0);
    __builtin_amdgcn_s_setprio(0);
    memfence_compiler();

    // ---- single end-of-tile sync: t+1 landed (counted), buffers safe ----
    asm volatile("s_waitcnt vmcnt(6)" ::: "memory");
    __builtin_amdgcn_s_barrier();
    memfence_compiler();

    // rotate ring: cur <- nxt <- stg <- cur
    unsigned short* tA = curA; curA = nxtA; nxtA = stgA; stgA = tA;
    unsigned short* tB = curB; curB = nxtB; nxtB = stgB; stgB = tB;
  }
  asm volatile("s_waitcnt vmcnt(0) lgkmcnt(0)" ::: "memory");

  // ---- epilogue: out = acc * g_7 + sum_e g_e b_e ----
  const int ocol0 = bn * BN + wn * 64;

  float bcol[4][NE];
#pragma unroll
  for (int ni = 0; ni < 4; ++ni) {
    const int col = ocol0 + ni * 16 + cc;
#pragma unroll
    for (int e = 0; e < NE; ++e) bcol[ni][e] = bias[e * DOUT + col];
  }

#pragma unroll
  for (int mi = 0; mi < 4; ++mi) {
#pragma unroll
    for (int q = 0; q < 4; ++q) {
      const int row = orow0 + mi * 16 + rq + q;
      const float gl = g_prev[mi * 4 + q];
      const float4 g0 = *reinterpret_cast<const float4*>(gates + (size_t)row * NE);
      const float4 g1 = *reinterpret_cast<const float4*>(gates + (size_t)row * NE + 4);
#pragma unroll
      for (int ni = 0; ni < 4; ++ni) {
        float s = g0.x * bcol[ni][0] + g0.y * bcol[ni][1]
                + g0.z * bcol[ni][2] + g0.w * bcol[ni][3]
                + g1.x * bcol[ni][4] + g1.y * bcol[ni][5]
                + g1.z * bcol[ni][6] + g1.w * bcol[ni][7];
        out[(size_t)row * DOUT + ocol0 + ni * 16 + cc] = acc[mi][ni][q] * gl + s;
      }
    }
  }
}

// ================= fallback path (used only if ws too small) =========
__global__ __launch_bounds__(256) void gates_kernel(
    const float* __restrict__ x, const float* __restrict__ gw,
    const float* __restrict__ gb, float* __restrict__ gates) {
  const int lane = threadIdx.x & 63;
  const int wave = threadIdx.x >> 6;
  const int n = blockIdx.x * 4 + wave;
  const float4* xr = reinterpret_cast<const float4*>(x + (size_t)n * DIN) + lane * 4;
  float4 xv0 = xr[0], xv1 = xr[1], xv2 = xr[2], xv3 = xr[3];
  float p[NE];
#pragma unroll
  for (int e = 0; e < NE; ++e) {
    const float4* wr = reinterpret_cast<const float4*>(gw + e * DIN) + lane * 4;
    p[e] = dot4(xv0, wr[0]) + dot4(xv1, wr[1]) + dot4(xv2, wr[2]) + dot4(xv3, wr[3]);
  }
#pragma unroll
  for (int off = 1; off < 64; off <<= 1) {
#pragma unroll
    for (int e = 0; e < NE; ++e) p[e] += __shfl_xor(p[e], off, 64);
  }
  float mx = -1e30f;
#pragma unroll
  for (int e = 0; e < NE; ++e) { p[e] += gb[e]; mx = fmaxf(mx, p[e]); }
  float s = 0.f;
#pragma unroll
  for (int e = 0; e < NE; ++e) { p[e] = __expf(p[e] - mx); s += p[e]; }
  float inv = 1.0f / s;
  if (lane < NE) gates[(size_t)n * NE + lane] = p[lane] * inv;
}

__global__ __launch_bounds__(256) void moe_gemm(
    const float* __restrict__ x, const float* __restrict__ w,
    const float* __restrict__ bias, const float* __restrict__ gates,
    float* __restrict__ out) {
  __shared__ __align__(16) unsigned short As[128][64];
  __shared__ __align__(16) unsigned short Bs[128][64];
  const int tid = threadIdx.x;
  const int bm = blockIdx.x, bn = blockIdx.y;
  const int lane = tid & 63;
  const int wv = tid >> 6, wm = wv >> 1, wn = wv & 1;
  const int lr = lane & 15, lkb = (lane >> 4) * 8;
  const int sr = tid >> 3, sc = (tid & 7) * 8;
  f32x4 acc[4][4];
#pragma unroll
  for (int i = 0; i < 4; ++i)
#pragma unroll
    for (int j = 0; j < 4; ++j) acc[i][j] = (f32x4){0.f, 0.f, 0.f, 0.f};
  float gA[4] = {0.f, 0.f, 0.f, 0.f};
  const int KT = (NE * DIN) / 64;
  for (int kt = 0; kt < KT; ++kt) {
    const int e = kt >> 4;
    const int kc = (kt << 6) & (DIN - 1);
    if ((kt & 15) == 0) {
#pragma unroll
      for (int i = 0; i < 4; ++i)
        gA[i] = gates[(size_t)(bm * 128 + i * 32 + sr) * NE + e];
    }
#pragma unroll
    for (int i = 0; i < 4; ++i) {
      const int r = i * 32 + sr;
      const float* src = x + (size_t)(bm * 128 + r) * DIN + kc + sc;
      float4 a0 = *reinterpret_cast<const float4*>(src);
      float4 a1 = *reinterpret_cast<const float4*>(src + 4);
      const float g = gA[i];
      short8 v;
      v[0] = (short)f2bf(a0.x * g); v[1] = (short)f2bf(a0.y * g);
      v[2] = (short)f2bf(a0.z * g); v[3] = (short)f2bf(a0.w * g);
      v[4] = (short)f2bf(a1.x * g); v[5] = (short)f2bf(a1.y * g);
      v[6] = (short)f2bf(a1.z * g); v[7] = (short)f2bf(a1.w * g);
      *reinterpret_cast<short8*>(&As[r][sc]) = v;
    }
#pragma unroll
    for (int i = 0; i < 4; ++i) {
      const int r = i * 32 + sr;
      const float* src = w + ((size_t)e * DOUT + bn * 128 + r) * DIN + kc + sc;
      float4 a0 = *reinterpret_cast<const float4*>(src);
      float4 a1 = *reinterpret_cast<const float4*>(src + 4);
      short8 v;
      v[0] = (short)f2bf(a0.x); v[1] = (short)f2bf(a0.y);
      v[2] = (short)f2bf(a0.z); v[3] = (short)f2bf(a0.w);
      v[4] = (short)f2bf(a1.x); v[5] = (short)f2bf(a1.y);
      v[6] = (short)f2bf(a1.z); v[7] = (short)f2bf(a1.w);
      *reinterpret_cast<short8*>(&Bs[r][sc]) = v;
    }
    __syncthreads();
#pragma unroll
    for (int kh = 0; kh < 2; ++kh) {
      short8 af[4], bfr[4];
#pragma unroll
      for (int mi = 0; mi < 4; ++mi)
        af[mi] = *reinterpret_cast<const short8*>(&As[wm * 64 + mi * 16 + lr][kh * 32 + lkb]);
#pragma unroll
      for (int ni = 0; ni < 4; ++ni)
        bfr[ni] = *reinterpret_cast<const short8*>(&Bs[wn * 64 + ni * 16 + lr][kh * 32 + lkb]);
#pragma unroll
      for (int mi = 0; mi < 4; ++mi)
#pragma unroll
        for (int ni = 0; ni < 4; ++ni)
          acc[mi][ni] = __builtin_amdgcn_mfma_f32_16x16x32_bf16(
              af[mi], bfr[ni], acc[mi][ni], 0, 0, 0);
    }
    __syncthreads();
  }
  const int orow0 = bm * 128 + wm * 64;
  const int ocol0 = bn * 128 + wn * 64;
  const int rq = (lane >> 4) * 4;
  const int cc = lane & 15;
  float bcol[4][NE];
#pragma unroll
  for (int ni = 0; ni < 4; ++ni) {
    const int col = ocol0 + ni * 16 + cc;
#pragma unroll
    for (int e = 0; e < NE; ++e) bcol[ni][e] = bias[e * DOUT + col];
  }
#pragma unroll
  for (int mi = 0; mi < 4; ++mi) {
#pragma unroll
    for (int q = 0; q < 4; ++q) {
      const int row = orow0 + mi * 16 + rq + q;
      const float4 g0 = *reinterpret_cast<const float4*>(gates + (size_t)row * NE);
      const float4 g1 = *reinterpret_cast<const float4*>(gates + (size_t)row * NE + 4);
#pragma unroll
      for (int ni = 0; ni < 4; ++ni) {
        float s = g0.x * bcol[ni][0] + g0.y * bcol[ni][1]
                + g0.z * bcol[ni][2] + g0.w * bcol[ni][3]
                + g1.x * bcol[ni][4] + g1.y * bcol[ni][5]
                + g1.z * bcol[ni][6] + g1.w * bcol[ni][7];
        out[(size_t)row * DOUT + ocol0 + ni * 16 + cc] = acc[mi][ni][q] + s;
      }
    }
  }
}

extern "C" void kernel_launch(void* const* d_in, const int* in_sizes, int n_in,
                              void* d_out, int out_size, void* d_ws, size_t ws_size,
                              hipStream_t stream) {
  const float* x  = (const float*)d_in[0];
  const float* ew = (const float*)d_in[1];
  const float* eb = (const float*)d_in[2];
  const float* gw = (const float*)d_in[3];
  const float* gb = (const float*)d_in[4];
  float* out = (float*)d_out;

  const size_t G_BYTES  = (size_t)N_TOK * NE * 4;
  const size_t XB_BYTES = (size_t)N_TOK * DIN * 2;
  const size_t WB_BYTES = (size_t)NE * DOUT * DIN * 2;

  if (ws_size >= G_BYTES + XB_BYTES + WB_BYTES) {
    float* gates = (float*)d_ws;
    unsigned short* xb = (unsigned short*)((char*)d_ws + G_BYTES);
    unsigned short* wb = (unsigned short*)((char*)d_ws + G_BYTES + XB_BYTES);

    gates_cvtx<<<N_TOK / 4, 256, 0, stream>>>(x, gw, gb, gates, xb);
    cvt_w<<<(NE * DOUT * DIN) / (256 * 8), 256, 0, stream>>>(ew, wb);
    moe_gemm_v15<<<(N_TOK / BM) * (DOUT / BN), 512, 0, stream>>>(xb, wb, eb, gates, out);
  } else {
    float* gates = (float*)d_ws;
    gates_kernel<<<N_TOK / 4, 256, 0, stream>>>(x, gw, gb, gates);
    dim3 grid(N_TOK / 128, DOUT / 128);
    moe_gemm<<<grid, 256, 0, stream>>>(x, ew, eb, gates, out);
  }
}

// Round 17
// 157.135 us; speedup vs baseline: 1.3019x; 1.3019x over previous
//
#include <hip/hip_runtime.h>

#define N_TOK 8192
#define DIN   1024
#define DOUT  1024
#define NE    8

#define BM 256
#define BN 128
#define BK 64

typedef __attribute__((ext_vector_type(8))) short  short8;
typedef __attribute__((ext_vector_type(4))) float  f32x4;
typedef unsigned int u32;

__device__ __forceinline__ unsigned short f2bf(float f) {
  union { float f; unsigned int u; } v; v.f = f;
  unsigned int u = v.u;
  unsigned int r = (u + 0x7fffu + ((u >> 16) & 1u)) >> 16;
  return (unsigned short)r;
}

__device__ __forceinline__ float dot4(float4 a, float4 b) {
  return a.x*b.x + a.y*b.y + a.z*b.z + a.w*b.w;
}

// async global -> LDS, 16B per lane; LDS dest = wave-uniform base + lane*16.
__device__ __forceinline__ void gload16(const unsigned short* g, unsigned short* l) {
  __builtin_amdgcn_global_load_lds(
      (const __attribute__((address_space(1))) u32*)g,
      (__attribute__((address_space(3))) u32*)l, 16, 0, 0);
}

__device__ __forceinline__ void memfence_compiler() {
  asm volatile("" ::: "memory");
}

// ---------------- gates + x->bf16 conversion (reads x once) ----------------
__global__ __launch_bounds__(256) void gates_cvtx(
    const float* __restrict__ x, const float* __restrict__ gw,
    const float* __restrict__ gb, float* __restrict__ gates,
    unsigned short* __restrict__ xb) {
  const int lane = threadIdx.x & 63;
  const int wave = threadIdx.x >> 6;
  const int n = blockIdx.x * 4 + wave;

  const float4* xr = reinterpret_cast<const float4*>(x + (size_t)n * DIN) + lane * 4;
  float4 xv0 = xr[0], xv1 = xr[1], xv2 = xr[2], xv3 = xr[3];

  short8 v0, v1;
  v0[0] = (short)f2bf(xv0.x); v0[1] = (short)f2bf(xv0.y);
  v0[2] = (short)f2bf(xv0.z); v0[3] = (short)f2bf(xv0.w);
  v0[4] = (short)f2bf(xv1.x); v0[5] = (short)f2bf(xv1.y);
  v0[6] = (short)f2bf(xv1.z); v0[7] = (short)f2bf(xv1.w);
  v1[0] = (short)f2bf(xv2.x); v1[1] = (short)f2bf(xv2.y);
  v1[2] = (short)f2bf(xv2.z); v1[3] = (short)f2bf(xv2.w);
  v1[4] = (short)f2bf(xv3.x); v1[5] = (short)f2bf(xv3.y);
  v1[6] = (short)f2bf(xv3.z); v1[7] = (short)f2bf(xv3.w);
  unsigned short* xo = xb + (size_t)n * DIN + lane * 16;
  *reinterpret_cast<short8*>(xo) = v0;
  *reinterpret_cast<short8*>(xo + 8) = v1;

  float p[NE];
#pragma unroll
  for (int e = 0; e < NE; ++e) {
    const float4* wr = reinterpret_cast<const float4*>(gw + e * DIN) + lane * 4;
    float4 w0 = wr[0], w1 = wr[1], w2 = wr[2], w3 = wr[3];
    p[e] = dot4(xv0, w0) + dot4(xv1, w1) + dot4(xv2, w2) + dot4(xv3, w3);
  }
#pragma unroll
  for (int off = 1; off < 64; off <<= 1) {
#pragma unroll
    for (int e = 0; e < NE; ++e) p[e] += __shfl_xor(p[e], off, 64);
  }
  float mx = -1e30f;
#pragma unroll
  for (int e = 0; e < NE; ++e) { p[e] += gb[e]; mx = fmaxf(mx, p[e]); }
  float s = 0.f;
#pragma unroll
  for (int e = 0; e < NE; ++e) { p[e] = __expf(p[e] - mx); s += p[e]; }
  float inv = 1.0f / s;
  if (lane < NE) gates[(size_t)n * NE + lane] = p[lane] * inv;
}

// ---------------- W -> bf16 ----------------
__global__ __launch_bounds__(256) void cvt_w(
    const float* __restrict__ w, unsigned short* __restrict__ wb) {
  const size_t i = ((size_t)blockIdx.x * 256 + threadIdx.x) * 8;
  float4 a0 = *reinterpret_cast<const float4*>(w + i);
  float4 a1 = *reinterpret_cast<const float4*>(w + i + 4);
  short8 v;
  v[0] = (short)f2bf(a0.x); v[1] = (short)f2bf(a0.y);
  v[2] = (short)f2bf(a0.z); v[3] = (short)f2bf(a0.w);
  v[4] = (short)f2bf(a1.x); v[5] = (short)f2bf(a1.y);
  v[6] = (short)f2bf(a1.z); v[7] = (short)f2bf(a1.w);
  *reinterpret_cast<short8*>(wb + i) = v;
}

// ---------------- main GEMM v10 (best known: 151.5 us, 907 TF).
// 256x128, 8 waves (4M x 2N), 64x64/wave. 3-deep LDS ring (144 KB).
// Per K-tile: {16 ds_read (kh0+kh1, same cur buffer - no mid-tile hazard) ->
// 6 gload(t+2) -> lgkmcnt(8) -> 16 MFMA kh0 -> lgkmcnt(0) -> 16 MFMA kh1 ->
// vmcnt(6) -> s_barrier}. Counted waits never drain mid-loop. Both-sides XOR
// swizzle (0 conflicts), Horner gate fold, XCD->bm-chunk map.
// Hazards: tile-t data landed via prior tile's vmcnt(6)+barrier; buffer reuse
// (stg(t+1)=cur(t-1)) guarded by the end-of-t barrier; each wave's ds_reads
// complete (lgkmcnt(0)) before it arrives at its barrier.
__global__ __launch_bounds__(512, 1) void moe_gemm_v10(
    const unsigned short* __restrict__ xb,   // [N_TOK][DIN] bf16
    const unsigned short* __restrict__ wb,   // [NE*DOUT][DIN] bf16
    const float* __restrict__ bias,          // [NE][DOUT]
    const float* __restrict__ gates,         // [N_TOK][NE]
    float* __restrict__ out) {               // [N_TOK][DOUT]
  __shared__ __align__(16) unsigned short As[3][BM * BK];  // 96 KB
  __shared__ __align__(16) unsigned short Bs[3][BN * BK];  // 48 KB

  const int tid = threadIdx.x;
  // XCD->bm-chunk map: xcd k owns bm in [4k,4k+4), all 8 bn (4MB set, L2-fit)
  const int d   = (int)blockIdx.x;
  const int xcd = d & 7;
  const int j   = d >> 3;              // 0..31
  const int bm  = xcd * 4 + (j & 3);   // 0..31
  const int bn  = j >> 2;              // 0..7

  const int lane = tid & 63;
  const int wv   = tid >> 6;       // 8 waves: 4 (M) x 2 (N)
  const int wm   = wv >> 1;        // 0..3
  const int wn   = wv & 1;         // 0..1
  const int lr   = lane & 15;
  const int g16  = lane >> 4;      // 0..3

  // staging: each instr covers 64 rows (8 rows/wave-slice); lane covers
  // row (.. + wv*8 + (lane>>3)), slot lane&7; pre-swizzled global col.
  const int sr8  = lane >> 3;
  const int scol = 8 * ((lane & 7) ^ (sr8 & 7));
  const unsigned short* a_src  = xb + (size_t)(bm * BM + wv * 8 + sr8) * DIN + scol;
  const unsigned short* b_src0 = wb + (size_t)(bn * BN + wv * 8 + sr8) * DIN + scol;

  const int rq = g16 * 4;
  const int cc = lane & 15;
  const int orow0 = bm * BM + wm * 64;

  // frag-read row offsets (elements)
  int rowA[4], rowB[4];
#pragma unroll
  for (int mi = 0; mi < 4; ++mi) rowA[mi] = (wm * 64 + mi * 16 + lr) * BK;
#pragma unroll
  for (int ni = 0; ni < 4; ++ni) rowB[ni] = (wn * 64 + ni * 16 + lr) * BK;
  const int sw0 = ((g16 ^ (lr & 7)) << 3);            // kh=0
  const int sw1 = (((4 + g16) ^ (lr & 7)) << 3);      // kh=1

  f32x4 acc[4][4];
#pragma unroll
  for (int i = 0; i < 4; ++i)
#pragma unroll
    for (int j2 = 0; j2 < 4; ++j2) acc[i][j2] = (f32x4){0.f, 0.f, 0.f, 0.f};

  float g_prev[16];
#pragma unroll
  for (int mi = 0; mi < 4; ++mi)
#pragma unroll
    for (int q = 0; q < 4; ++q)
      g_prev[mi * 4 + q] = gates[(size_t)(orow0 + mi * 16 + rq + q) * NE];

  // rotating ring pointers
  unsigned short *curA = &As[0][0], *nxtA = &As[1][0], *stgA = &As[2][0];
  unsigned short *curB = &Bs[0][0], *nxtB = &Bs[1][0], *stgB = &Bs[2][0];

  // prologue: stage t0 -> buf0, t1 -> buf1 (6+6 loads per thread)
#pragma unroll
  for (int i = 0; i < 4; ++i)
    gload16(a_src + (size_t)i * 64 * DIN, curA + (i * 64 + wv * 8) * BK);
#pragma unroll
  for (int j2 = 0; j2 < 2; ++j2)
    gload16(b_src0 + (size_t)j2 * 64 * DIN, curB + (j2 * 64 + wv * 8) * BK);
  {
    const unsigned short* ak = a_src + 1 * BK;          // t=1: e0,kk1
    const unsigned short* bk = b_src0 + 1 * BK;
#pragma unroll
    for (int i = 0; i < 4; ++i)
      gload16(ak + (size_t)i * 64 * DIN, nxtA + (i * 64 + wv * 8) * BK);
#pragma unroll
    for (int j2 = 0; j2 < 2; ++j2)
      gload16(bk + (size_t)j2 * 64 * DIN, nxtB + (j2 * 64 + wv * 8) * BK);
  }
  asm volatile("s_waitcnt vmcnt(6)" ::: "memory");   // t0 landed
  __builtin_amdgcn_s_barrier();
  memfence_compiler();

  for (int t = 0; t < 128; ++t) {
    const int e  = t >> 4;

    // ---- Horner gate boundary: acc *= g_{e-1}/g_e ----
    if ((t & 15) == 0 && e) {
#pragma unroll
      for (int mi = 0; mi < 4; ++mi)
#pragma unroll
        for (int q = 0; q < 4; ++q) {
          const int row = orow0 + mi * 16 + rq + q;
          const float gn = fmaxf(gates[(size_t)row * NE + e], 1e-37f);
          const float r = g_prev[mi * 4 + q] / gn;
          g_prev[mi * 4 + q] = gn;
#pragma unroll
          for (int ni = 0; ni < 4; ++ni) acc[mi][ni][q] *= r;
        }
    }

    // source for tile t+2 (wraps to dummy restage at tail)
    int tn = t + 2; if (tn >= 128) tn -= 128;
    const int en = tn >> 4;
    const int kn = tn & 15;
    const unsigned short* ak = a_src + kn * BK;
    const unsigned short* bk = b_src0 + (size_t)en * DOUT * DIN + kn * BK;

    // ---- issue ALL frag reads for this tile (kh0 first, then kh1) ----
    short8 af0[4], bf0[4], af1[4], bf1[4];
#pragma unroll
    for (int mi = 0; mi < 4; ++mi)
      af0[mi] = *reinterpret_cast<const short8*>(&curA[rowA[mi] + sw0]);
#pragma unroll
    for (int ni = 0; ni < 4; ++ni)
      bf0[ni] = *reinterpret_cast<const short8*>(&curB[rowB[ni] + sw0]);
#pragma unroll
    for (int mi = 0; mi < 4; ++mi)
      af1[mi] = *reinterpret_cast<const short8*>(&curA[rowA[mi] + sw1]);
#pragma unroll
    for (int ni = 0; ni < 4; ++ni)
      bf1[ni] = *reinterpret_cast<const short8*>(&curB[rowB[ni] + sw1]);

    // ---- stage tile t+2 into stg (6 gloads; vmcnt only) ----
    gload16(ak,                     stgA + (wv * 8) * BK);
    gload16(ak + (size_t)64 * DIN,  stgA + (64 + wv * 8) * BK);
    gload16(ak + (size_t)128 * DIN, stgA + (128 + wv * 8) * BK);
    gload16(ak + (size_t)192 * DIN, stgA + (192 + wv * 8) * BK);
    gload16(bk,                     stgB + (wv * 8) * BK);
    gload16(bk + (size_t)64 * DIN,  stgB + (64 + wv * 8) * BK);
    memfence_compiler();

    // ---- kh0 cluster: wait only the first 8 ds_reads (kh1's 8 in flight)
    asm volatile("s_waitcnt lgkmcnt(8)" ::: "memory");
    __builtin_amdgcn_sched_barrier(0);
    __builtin_amdgcn_s_setprio(1);
#pragma unroll
    for (int mi = 0; mi < 4; ++mi)
#pragma unroll
      for (int ni = 0; ni < 4; ++ni)
        acc[mi][ni] = __builtin_amdgcn_mfma_f32_16x16x32_bf16(
            af0[mi], bf0[ni], acc[mi][ni], 0, 0, 0);
    __builtin_amdgcn_s_setprio(0);

    // ---- kh1 cluster ----
    asm volatile("s_waitcnt lgkmcnt(0)" ::: "memory");
    __builtin_amdgcn_sched_barrier(0);
    __builtin_amdgcn_s_setprio(1);
#pragma unroll
    for (int mi = 0; mi < 4; ++mi)
#pragma unroll
      for (int ni = 0; ni < 4; ++ni)
        acc[mi][ni] = __builtin_amdgcn_mfma_f32_16x16x32_bf16(
            af1[mi], bf1[ni], acc[mi][ni], 0, 0, 0);
    __builtin_amdgcn_s_setprio(0);
    memfence_compiler();

    // ---- single end-of-tile sync: t+1 landed (counted), buffers safe ----
    asm volatile("s_waitcnt vmcnt(6)" ::: "memory");
    __builtin_amdgcn_s_barrier();
    memfence_compiler();

    // rotate ring: cur <- nxt <- stg <- cur
    unsigned short* tA = curA; curA = nxtA; nxtA = stgA; stgA = tA;
    unsigned short* tB = curB; curB = nxtB; nxtB = stgB; stgB = tB;
  }
  asm volatile("s_waitcnt vmcnt(0) lgkmcnt(0)" ::: "memory");

  // ---- epilogue: out = acc * g_7 + sum_e g_e b_e ----
  const int ocol0 = bn * BN + wn * 64;

  float bcol[4][NE];
#pragma unroll
  for (int ni = 0; ni < 4; ++ni) {
    const int col = ocol0 + ni * 16 + cc;
#pragma unroll
    for (int e = 0; e < NE; ++e) bcol[ni][e] = bias[e * DOUT + col];
  }

#pragma unroll
  for (int mi = 0; mi < 4; ++mi) {
#pragma unroll
    for (int q = 0; q < 4; ++q) {
      const int row = orow0 + mi * 16 + rq + q;
      const float gl = g_prev[mi * 4 + q];
      const float4 g0 = *reinterpret_cast<const float4*>(gates + (size_t)row * NE);
      const float4 g1 = *reinterpret_cast<const float4*>(gates + (size_t)row * NE + 4);
#pragma unroll
      for (int ni = 0; ni < 4; ++ni) {
        float s = g0.x * bcol[ni][0] + g0.y * bcol[ni][1]
                + g0.z * bcol[ni][2] + g0.w * bcol[ni][3]
                + g1.x * bcol[ni][4] + g1.y * bcol[ni][5]
                + g1.z * bcol[ni][6] + g1.w * bcol[ni][7];
        out[(size_t)row * DOUT + ocol0 + ni * 16 + cc] = acc[mi][ni][q] * gl + s;
      }
    }
  }
}

// ================= fallback path (used only if ws too small) =========
__global__ __launch_bounds__(256) void gates_kernel(
    const float* __restrict__ x, const float* __restrict__ gw,
    const float* __restrict__ gb, float* __restrict__ gates) {
  const int lane = threadIdx.x & 63;
  const int wave = threadIdx.x >> 6;
  const int n = blockIdx.x * 4 + wave;
  const float4* xr = reinterpret_cast<const float4*>(x + (size_t)n * DIN) + lane * 4;
  float4 xv0 = xr[0], xv1 = xr[1], xv2 = xr[2], xv3 = xr[3];
  float p[NE];
#pragma unroll
  for (int e = 0; e < NE; ++e) {
    const float4* wr = reinterpret_cast<const float4*>(gw + e * DIN) + lane * 4;
    p[e] = dot4(xv0, wr[0]) + dot4(xv1, wr[1]) + dot4(xv2, wr[2]) + dot4(xv3, wr[3]);
  }
#pragma unroll
  for (int off = 1; off < 64; off <<= 1) {
#pragma unroll
    for (int e = 0; e < NE; ++e) p[e] += __shfl_xor(p[e], off, 64);
  }
  float mx = -1e30f;
#pragma unroll
  for (int e = 0; e < NE; ++e) { p[e] += gb[e]; mx = fmaxf(mx, p[e]); }
  float s = 0.f;
#pragma unroll
  for (int e = 0; e < NE; ++e) { p[e] = __expf(p[e] - mx); s += p[e]; }
  float inv = 1.0f / s;
  if (lane < NE) gates[(size_t)n * NE + lane] = p[lane] * inv;
}

__global__ __launch_bounds__(256) void moe_gemm(
    const float* __restrict__ x, const float* __restrict__ w,
    const float* __restrict__ bias, const float* __restrict__ gates,
    float* __restrict__ out) {
  __shared__ __align__(16) unsigned short As[128][64];
  __shared__ __align__(16) unsigned short Bs[128][64];
  const int tid = threadIdx.x;
  const int bm = blockIdx.x, bn = blockIdx.y;
  const int lane = tid & 63;
  const int wv = tid >> 6, wm = wv >> 1, wn = wv & 1;
  const int lr = lane & 15, lkb = (lane >> 4) * 8;
  const int sr = tid >> 3, sc = (tid & 7) * 8;
  f32x4 acc[4][4];
#pragma unroll
  for (int i = 0; i < 4; ++i)
#pragma unroll
    for (int j = 0; j < 4; ++j) acc[i][j] = (f32x4){0.f, 0.f, 0.f, 0.f};
  float gA[4] = {0.f, 0.f, 0.f, 0.f};
  const int KT = (NE * DIN) / 64;
  for (int kt = 0; kt < KT; ++kt) {
    const int e = kt >> 4;
    const int kc = (kt << 6) & (DIN - 1);
    if ((kt & 15) == 0) {
#pragma unroll
      for (int i = 0; i < 4; ++i)
        gA[i] = gates[(size_t)(bm * 128 + i * 32 + sr) * NE + e];
    }
#pragma unroll
    for (int i = 0; i < 4; ++i) {
      const int r = i * 32 + sr;
      const float* src = x + (size_t)(bm * 128 + r) * DIN + kc + sc;
      float4 a0 = *reinterpret_cast<const float4*>(src);
      float4 a1 = *reinterpret_cast<const float4*>(src + 4);
      const float g = gA[i];
      short8 v;
      v[0] = (short)f2bf(a0.x * g); v[1] = (short)f2bf(a0.y * g);
      v[2] = (short)f2bf(a0.z * g); v[3] = (short)f2bf(a0.w * g);
      v[4] = (short)f2bf(a1.x * g); v[5] = (short)f2bf(a1.y * g);
      v[6] = (short)f2bf(a1.z * g); v[7] = (short)f2bf(a1.w * g);
      *reinterpret_cast<short8*>(&As[r][sc]) = v;
    }
#pragma unroll
    for (int i = 0; i < 4; ++i) {
      const int r = i * 32 + sr;
      const float* src = w + ((size_t)e * DOUT + bn * 128 + r) * DIN + kc + sc;
      float4 a0 = *reinterpret_cast<const float4*>(src);
      float4 a1 = *reinterpret_cast<const float4*>(src + 4);
      short8 v;
      v[0] = (short)f2bf(a0.x); v[1] = (short)f2bf(a0.y);
      v[2] = (short)f2bf(a0.z); v[3] = (short)f2bf(a0.w);
      v[4] = (short)f2bf(a1.x); v[5] = (short)f2bf(a1.y);
      v[6] = (short)f2bf(a1.z); v[7] = (short)f2bf(a1.w);
      *reinterpret_cast<short8*>(&Bs[r][sc]) = v;
    }
    __syncthreads();
#pragma unroll
    for (int kh = 0; kh < 2; ++kh) {
      short8 af[4], bfr[4];
#pragma unroll
      for (int mi = 0; mi < 4; ++mi)
        af[mi] = *reinterpret_cast<const short8*>(&As[wm * 64 + mi * 16 + lr][kh * 32 + lkb]);
#pragma unroll
      for (int ni = 0; ni < 4; ++ni)
        bfr[ni] = *reinterpret_cast<const short8*>(&Bs[wn * 64 + ni * 16 + lr][kh * 32 + lkb]);
#pragma unroll
      for (int mi = 0; mi < 4; ++mi)
#pragma unroll
        for (int ni = 0; ni < 4; ++ni)
          acc[mi][ni] = __builtin_amdgcn_mfma_f32_16x16x32_bf16(
              af[mi], bfr[ni], acc[mi][ni], 0, 0, 0);
    }
    __syncthreads();
  }
  const int orow0 = bm * 128 + wm * 64;
  const int ocol0 = bn * 128 + wn * 64;
  const int rq = (lane >> 4) * 4;
  const int cc = lane & 15;
  float bcol[4][NE];
#pragma unroll
  for (int ni = 0; ni < 4; ++ni) {
    const int col = ocol0 + ni * 16 + cc;
#pragma unroll
    for (int e = 0; e < NE; ++e) bcol[ni][e] = bias[e * DOUT + col];
  }
#pragma unroll
  for (int mi = 0; mi < 4; ++mi) {
#pragma unroll
    for (int q = 0; q < 4; ++q) {
      const int row = orow0 + mi * 16 + rq + q;
      const float4 g0 = *reinterpret_cast<const float4*>(gates + (size_t)row * NE);
      const float4 g1 = *reinterpret_cast<const float4*>(gates + (size_t)row * NE + 4);
#pragma unroll
      for (int ni = 0; ni < 4; ++ni) {
        float s = g0.x * bcol[ni][0] + g0.y * bcol[ni][1]
                + g0.z * bcol[ni][2] + g0.w * bcol[ni][3]
                + g1.x * bcol[ni][4] + g1.y * bcol[ni][5]
                + g1.z * bcol[ni][6] + g1.w * bcol[ni][7];
        out[(size_t)row * DOUT + ocol0 + ni * 16 + cc] = acc[mi][ni][q] + s;
      }
    }
  }
}

extern "C" void kernel_launch(void* const* d_in, const int* in_sizes, int n_in,
                              void* d_out, int out_size, void* d_ws, size_t ws_size,
                              hipStream_t stream) {
  const float* x  = (const float*)d_in[0];
  const float* ew = (const float*)d_in[1];
  const float* eb = (const float*)d_in[2];
  const float* gw = (const float*)d_in[3];
  const float* gb = (const float*)d_in[4];
  float* out = (float*)d_out;

  const size_t G_BYTES  = (size_t)N_TOK * NE * 4;
  const size_t XB_BYTES = (size_t)N_TOK * DIN * 2;
  const size_t WB_BYTES = (size_t)NE * DOUT * DIN * 2;

  if (ws_size >= G_BYTES + XB_BYTES + WB_BYTES) {
    float* gates = (float*)d_ws;
    unsigned short* xb = (unsigned short*)((char*)d_ws + G_BYTES);
    unsigned short* wb = (unsigned short*)((char*)d_ws + G_BYTES + XB_BYTES);

    gates_cvtx<<<N_TOK / 4, 256, 0, stream>>>(x, gw, gb, gates, xb);
    cvt_w<<<(NE * DOUT * DIN) / (256 * 8), 256, 0, stream>>>(ew, wb);
    moe_gemm_v10<<<(N_TOK / BM) * (DOUT / BN), 512, 0, stream>>>(xb, wb, eb, gates, out);
  } else {
    float* gates = (float*)d_ws;
    gates_kernel<<<N_TOK / 4, 256, 0, stream>>>(x, gw, gb, gates);
    dim3 grid(N_TOK / 128, DOUT / 128);
    moe_gemm<<<grid, 256, 0, stream>>>(x, ew, eb, gates, out);
  }
}

// Round 18
// 153.097 us; speedup vs baseline: 1.3362x; 1.0264x over previous
//
#include <hip/hip_runtime.h>

#define N_TOK 8192
#define DIN   1024
#define DOUT  1024
#define NE    8

#define BM 256
#define BN 128
#define BK 64

typedef __attribute__((ext_vector_type(8))) short  short8;
typedef __attribute__((ext_vector_type(4))) float  f32x4;
typedef unsigned int u32;

__device__ __forceinline__ unsigned short f2bf(float f) {
  union { float f; unsigned int u; } v; v.f = f;
  unsigned int u = v.u;
  unsigned int r = (u + 0x7fffu + ((u >> 16) & 1u)) >> 16;
  return (unsigned short)r;
}

__device__ __forceinline__ float dot4(float4 a, float4 b) {
  return a.x*b.x + a.y*b.y + a.z*b.z + a.w*b.w;
}

// async global -> LDS, 16B per lane; LDS dest = wave-uniform base + lane*16.
__device__ __forceinline__ void gload16(const unsigned short* g, unsigned short* l) {
  __builtin_amdgcn_global_load_lds(
      (const __attribute__((address_space(1))) u32*)g,
      (__attribute__((address_space(3))) u32*)l, 16, 0, 0);
}

__device__ __forceinline__ void memfence_compiler() {
  asm volatile("" ::: "memory");
}

// ---------------- fused prep: gates+x->bf16 (blocks 0..2047) and
// W->bf16 (blocks 2048..6143). One launch instead of two. ----------------
__global__ __launch_bounds__(256) void prep_fused(
    const float* __restrict__ x, const float* __restrict__ w,
    const float* __restrict__ gw, const float* __restrict__ gb,
    float* __restrict__ gates, unsigned short* __restrict__ xb,
    unsigned short* __restrict__ wb) {
  const int b = (int)blockIdx.x;
  if (b < N_TOK / 4) {
    // ---- gates + x conversion: one wave per token ----
    const int lane = threadIdx.x & 63;
    const int wave = threadIdx.x >> 6;
    const int n = b * 4 + wave;

    const float4* xr = reinterpret_cast<const float4*>(x + (size_t)n * DIN) + lane * 4;
    float4 xv0 = xr[0], xv1 = xr[1], xv2 = xr[2], xv3 = xr[3];

    short8 v0, v1;
    v0[0] = (short)f2bf(xv0.x); v0[1] = (short)f2bf(xv0.y);
    v0[2] = (short)f2bf(xv0.z); v0[3] = (short)f2bf(xv0.w);
    v0[4] = (short)f2bf(xv1.x); v0[5] = (short)f2bf(xv1.y);
    v0[6] = (short)f2bf(xv1.z); v0[7] = (short)f2bf(xv1.w);
    v1[0] = (short)f2bf(xv2.x); v1[1] = (short)f2bf(xv2.y);
    v1[2] = (short)f2bf(xv2.z); v1[3] = (short)f2bf(xv2.w);
    v1[4] = (short)f2bf(xv3.x); v1[5] = (short)f2bf(xv3.y);
    v1[6] = (short)f2bf(xv3.z); v1[7] = (short)f2bf(xv3.w);
    unsigned short* xo = xb + (size_t)n * DIN + lane * 16;
    *reinterpret_cast<short8*>(xo) = v0;
    *reinterpret_cast<short8*>(xo + 8) = v1;

    float p[NE];
#pragma unroll
    for (int e = 0; e < NE; ++e) {
      const float4* wr = reinterpret_cast<const float4*>(gw + e * DIN) + lane * 4;
      float4 w0 = wr[0], w1 = wr[1], w2 = wr[2], w3 = wr[3];
      p[e] = dot4(xv0, w0) + dot4(xv1, w1) + dot4(xv2, w2) + dot4(xv3, w3);
    }
#pragma unroll
    for (int off = 1; off < 64; off <<= 1) {
#pragma unroll
      for (int e = 0; e < NE; ++e) p[e] += __shfl_xor(p[e], off, 64);
    }
    float mx = -1e30f;
#pragma unroll
    for (int e = 0; e < NE; ++e) { p[e] += gb[e]; mx = fmaxf(mx, p[e]); }
    float s = 0.f;
#pragma unroll
    for (int e = 0; e < NE; ++e) { p[e] = __expf(p[e] - mx); s += p[e]; }
    float inv = 1.0f / s;
    if (lane < NE) gates[(size_t)n * NE + lane] = p[lane] * inv;
  } else {
    // ---- W conversion: 8 fp32 -> 8 bf16 per thread ----
    const size_t i = ((size_t)(b - N_TOK / 4) * 256 + threadIdx.x) * 8;
    float4 a0 = *reinterpret_cast<const float4*>(w + i);
    float4 a1 = *reinterpret_cast<const float4*>(w + i + 4);
    short8 v;
    v[0] = (short)f2bf(a0.x); v[1] = (short)f2bf(a0.y);
    v[2] = (short)f2bf(a0.z); v[3] = (short)f2bf(a0.w);
    v[4] = (short)f2bf(a1.x); v[5] = (short)f2bf(a1.y);
    v[6] = (short)f2bf(a1.z); v[7] = (short)f2bf(a1.w);
    *reinterpret_cast<short8*>(wb + i) = v;
  }
}

// ---------------- main GEMM v10 (best known: ~150 us, ~915 TF).
// 256x128, 8 waves (4M x 2N), 64x64/wave. 3-deep LDS ring (144 KB).
// Per K-tile: {16 ds_read (kh0+kh1, same cur buffer - no mid-tile hazard) ->
// 6 gload(t+2) -> lgkmcnt(8) -> 16 MFMA kh0 -> lgkmcnt(0) -> 16 MFMA kh1 ->
// vmcnt(6) -> s_barrier}. Counted waits never drain mid-loop. Both-sides XOR
// swizzle (0 conflicts), Horner gate fold, XCD->bm-chunk map.
// Hazards: tile-t data landed via prior tile's vmcnt(6)+barrier; buffer reuse
// (stg(t+1)=cur(t-1)) guarded by the end-of-t barrier; each wave's ds_reads
// complete (lgkmcnt(0)) before it arrives at its barrier.
__global__ __launch_bounds__(512, 1) void moe_gemm_v10(
    const unsigned short* __restrict__ xb,   // [N_TOK][DIN] bf16
    const unsigned short* __restrict__ wb,   // [NE*DOUT][DIN] bf16
    const float* __restrict__ bias,          // [NE][DOUT]
    const float* __restrict__ gates,         // [N_TOK][NE]
    float* __restrict__ out) {               // [N_TOK][DOUT]
  __shared__ __align__(16) unsigned short As[3][BM * BK];  // 96 KB
  __shared__ __align__(16) unsigned short Bs[3][BN * BK];  // 48 KB

  const int tid = threadIdx.x;
  // XCD->bm-chunk map: xcd k owns bm in [4k,4k+4), all 8 bn (4MB set, L2-fit)
  const int d   = (int)blockIdx.x;
  const int xcd = d & 7;
  const int j   = d >> 3;              // 0..31
  const int bm  = xcd * 4 + (j & 3);   // 0..31
  const int bn  = j >> 2;              // 0..7

  const int lane = tid & 63;
  const int wv   = tid >> 6;       // 8 waves: 4 (M) x 2 (N)
  const int wm   = wv >> 1;        // 0..3
  const int wn   = wv & 1;         // 0..1
  const int lr   = lane & 15;
  const int g16  = lane >> 4;      // 0..3

  // staging: each instr covers 64 rows (8 rows/wave-slice); lane covers
  // row (.. + wv*8 + (lane>>3)), slot lane&7; pre-swizzled global col.
  const int sr8  = lane >> 3;
  const int scol = 8 * ((lane & 7) ^ (sr8 & 7));
  const unsigned short* a_src  = xb + (size_t)(bm * BM + wv * 8 + sr8) * DIN + scol;
  const unsigned short* b_src0 = wb + (size_t)(bn * BN + wv * 8 + sr8) * DIN + scol;

  const int rq = g16 * 4;
  const int cc = lane & 15;
  const int orow0 = bm * BM + wm * 64;

  // frag-read row offsets (elements)
  int rowA[4], rowB[4];
#pragma unroll
  for (int mi = 0; mi < 4; ++mi) rowA[mi] = (wm * 64 + mi * 16 + lr) * BK;
#pragma unroll
  for (int ni = 0; ni < 4; ++ni) rowB[ni] = (wn * 64 + ni * 16 + lr) * BK;
  const int sw0 = ((g16 ^ (lr & 7)) << 3);            // kh=0
  const int sw1 = (((4 + g16) ^ (lr & 7)) << 3);      // kh=1

  f32x4 acc[4][4];
#pragma unroll
  for (int i = 0; i < 4; ++i)
#pragma unroll
    for (int j2 = 0; j2 < 4; ++j2) acc[i][j2] = (f32x4){0.f, 0.f, 0.f, 0.f};

  float g_prev[16];
#pragma unroll
  for (int mi = 0; mi < 4; ++mi)
#pragma unroll
    for (int q = 0; q < 4; ++q)
      g_prev[mi * 4 + q] = gates[(size_t)(orow0 + mi * 16 + rq + q) * NE];

  // rotating ring pointers
  unsigned short *curA = &As[0][0], *nxtA = &As[1][0], *stgA = &As[2][0];
  unsigned short *curB = &Bs[0][0], *nxtB = &Bs[1][0], *stgB = &Bs[2][0];

  // prologue: stage t0 -> buf0, t1 -> buf1 (6+6 loads per thread)
#pragma unroll
  for (int i = 0; i < 4; ++i)
    gload16(a_src + (size_t)i * 64 * DIN, curA + (i * 64 + wv * 8) * BK);
#pragma unroll
  for (int j2 = 0; j2 < 2; ++j2)
    gload16(b_src0 + (size_t)j2 * 64 * DIN, curB + (j2 * 64 + wv * 8) * BK);
  {
    const unsigned short* ak = a_src + 1 * BK;          // t=1: e0,kk1
    const unsigned short* bk = b_src0 + 1 * BK;
#pragma unroll
    for (int i = 0; i < 4; ++i)
      gload16(ak + (size_t)i * 64 * DIN, nxtA + (i * 64 + wv * 8) * BK);
#pragma unroll
    for (int j2 = 0; j2 < 2; ++j2)
      gload16(bk + (size_t)j2 * 64 * DIN, nxtB + (j2 * 64 + wv * 8) * BK);
  }
  asm volatile("s_waitcnt vmcnt(6)" ::: "memory");   // t0 landed
  __builtin_amdgcn_s_barrier();
  memfence_compiler();

  for (int t = 0; t < 128; ++t) {
    const int e  = t >> 4;

    // ---- Horner gate boundary: acc *= g_{e-1}/g_e ----
    if ((t & 15) == 0 && e) {
#pragma unroll
      for (int mi = 0; mi < 4; ++mi)
#pragma unroll
        for (int q = 0; q < 4; ++q) {
          const int row = orow0 + mi * 16 + rq + q;
          const float gn = fmaxf(gates[(size_t)row * NE + e], 1e-37f);
          const float r = g_prev[mi * 4 + q] / gn;
          g_prev[mi * 4 + q] = gn;
#pragma unroll
          for (int ni = 0; ni < 4; ++ni) acc[mi][ni][q] *= r;
        }
    }

    // source for tile t+2 (wraps to dummy restage at tail)
    int tn = t + 2; if (tn >= 128) tn -= 128;
    const int en = tn >> 4;
    const int kn = tn & 15;
    const unsigned short* ak = a_src + kn * BK;
    const unsigned short* bk = b_src0 + (size_t)en * DOUT * DIN + kn * BK;

    // ---- issue ALL frag reads for this tile (kh0 first, then kh1) ----
    short8 af0[4], bf0[4], af1[4], bf1[4];
#pragma unroll
    for (int mi = 0; mi < 4; ++mi)
      af0[mi] = *reinterpret_cast<const short8*>(&curA[rowA[mi] + sw0]);
#pragma unroll
    for (int ni = 0; ni < 4; ++ni)
      bf0[ni] = *reinterpret_cast<const short8*>(&curB[rowB[ni] + sw0]);
#pragma unroll
    for (int mi = 0; mi < 4; ++mi)
      af1[mi] = *reinterpret_cast<const short8*>(&curA[rowA[mi] + sw1]);
#pragma unroll
    for (int ni = 0; ni < 4; ++ni)
      bf1[ni] = *reinterpret_cast<const short8*>(&curB[rowB[ni] + sw1]);

    // ---- stage tile t+2 into stg (6 gloads; vmcnt only) ----
    gload16(ak,                     stgA + (wv * 8) * BK);
    gload16(ak + (size_t)64 * DIN,  stgA + (64 + wv * 8) * BK);
    gload16(ak + (size_t)128 * DIN, stgA + (128 + wv * 8) * BK);
    gload16(ak + (size_t)192 * DIN, stgA + (192 + wv * 8) * BK);
    gload16(bk,                     stgB + (wv * 8) * BK);
    gload16(bk + (size_t)64 * DIN,  stgB + (64 + wv * 8) * BK);
    memfence_compiler();

    // ---- kh0 cluster: wait only the first 8 ds_reads (kh1's 8 in flight)
    asm volatile("s_waitcnt lgkmcnt(8)" ::: "memory");
    __builtin_amdgcn_sched_barrier(0);
    __builtin_amdgcn_s_setprio(1);
#pragma unroll
    for (int mi = 0; mi < 4; ++mi)
#pragma unroll
      for (int ni = 0; ni < 4; ++ni)
        acc[mi][ni] = __builtin_amdgcn_mfma_f32_16x16x32_bf16(
            af0[mi], bf0[ni], acc[mi][ni], 0, 0, 0);
    __builtin_amdgcn_s_setprio(0);

    // ---- kh1 cluster ----
    asm volatile("s_waitcnt lgkmcnt(0)" ::: "memory");
    __builtin_amdgcn_sched_barrier(0);
    __builtin_amdgcn_s_setprio(1);
#pragma unroll
    for (int mi = 0; mi < 4; ++mi)
#pragma unroll
      for (int ni = 0; ni < 4; ++ni)
        acc[mi][ni] = __builtin_amdgcn_mfma_f32_16x16x32_bf16(
            af1[mi], bf1[ni], acc[mi][ni], 0, 0, 0);
    __builtin_amdgcn_s_setprio(0);
    memfence_compiler();

    // ---- single end-of-tile sync: t+1 landed (counted), buffers safe ----
    asm volatile("s_waitcnt vmcnt(6)" ::: "memory");
    __builtin_amdgcn_s_barrier();
    memfence_compiler();

    // rotate ring: cur <- nxt <- stg <- cur
    unsigned short* tA = curA; curA = nxtA; nxtA = stgA; stgA = tA;
    unsigned short* tB = curB; curB = nxtB; nxtB = stgB; stgB = tB;
  }
  asm volatile("s_waitcnt vmcnt(0) lgkmcnt(0)" ::: "memory");

  // ---- epilogue: out = acc * g_7 + sum_e g_e b_e ----
  const int ocol0 = bn * BN + wn * 64;

  float bcol[4][NE];
#pragma unroll
  for (int ni = 0; ni < 4; ++ni) {
    const int col = ocol0 + ni * 16 + cc;
#pragma unroll
    for (int e = 0; e < NE; ++e) bcol[ni][e] = bias[e * DOUT + col];
  }

#pragma unroll
  for (int mi = 0; mi < 4; ++mi) {
#pragma unroll
    for (int q = 0; q < 4; ++q) {
      const int row = orow0 + mi * 16 + rq + q;
      const float gl = g_prev[mi * 4 + q];
      const float4 g0 = *reinterpret_cast<const float4*>(gates + (size_t)row * NE);
      const float4 g1 = *reinterpret_cast<const float4*>(gates + (size_t)row * NE + 4);
#pragma unroll
      for (int ni = 0; ni < 4; ++ni) {
        float s = g0.x * bcol[ni][0] + g0.y * bcol[ni][1]
                + g0.z * bcol[ni][2] + g0.w * bcol[ni][3]
                + g1.x * bcol[ni][4] + g1.y * bcol[ni][5]
                + g1.z * bcol[ni][6] + g1.w * bcol[ni][7];
        out[(size_t)row * DOUT + ocol0 + ni * 16 + cc] = acc[mi][ni][q] * gl + s;
      }
    }
  }
}

// ================= fallback path (used only if ws too small) =========
__global__ __launch_bounds__(256) void gates_kernel(
    const float* __restrict__ x, const float* __restrict__ gw,
    const float* __restrict__ gb, float* __restrict__ gates) {
  const int lane = threadIdx.x & 63;
  const int wave = threadIdx.x >> 6;
  const int n = blockIdx.x * 4 + wave;
  const float4* xr = reinterpret_cast<const float4*>(x + (size_t)n * DIN) + lane * 4;
  float4 xv0 = xr[0], xv1 = xr[1], xv2 = xr[2], xv3 = xr[3];
  float p[NE];
#pragma unroll
  for (int e = 0; e < NE; ++e) {
    const float4* wr = reinterpret_cast<const float4*>(gw + e * DIN) + lane * 4;
    p[e] = dot4(xv0, wr[0]) + dot4(xv1, wr[1]) + dot4(xv2, wr[2]) + dot4(xv3, wr[3]);
  }
#pragma unroll
  for (int off = 1; off < 64; off <<= 1) {
#pragma unroll
    for (int e = 0; e < NE; ++e) p[e] += __shfl_xor(p[e], off, 64);
  }
  float mx = -1e30f;
#pragma unroll
  for (int e = 0; e < NE; ++e) { p[e] += gb[e]; mx = fmaxf(mx, p[e]); }
  float s = 0.f;
#pragma unroll
  for (int e = 0; e < NE; ++e) { p[e] = __expf(p[e] - mx); s += p[e]; }
  float inv = 1.0f / s;
  if (lane < NE) gates[(size_t)n * NE + lane] = p[lane] * inv;
}

__global__ __launch_bounds__(256) void moe_gemm(
    const float* __restrict__ x, const float* __restrict__ w,
    const float* __restrict__ bias, const float* __restrict__ gates,
    float* __restrict__ out) {
  __shared__ __align__(16) unsigned short As[128][64];
  __shared__ __align__(16) unsigned short Bs[128][64];
  const int tid = threadIdx.x;
  const int bm = blockIdx.x, bn = blockIdx.y;
  const int lane = tid & 63;
  const int wv = tid >> 6, wm = wv >> 1, wn = wv & 1;
  const int lr = lane & 15, lkb = (lane >> 4) * 8;
  const int sr = tid >> 3, sc = (tid & 7) * 8;
  f32x4 acc[4][4];
#pragma unroll
  for (int i = 0; i < 4; ++i)
#pragma unroll
    for (int j = 0; j < 4; ++j) acc[i][j] = (f32x4){0.f, 0.f, 0.f, 0.f};
  float gA[4] = {0.f, 0.f, 0.f, 0.f};
  const int KT = (NE * DIN) / 64;
  for (int kt = 0; kt < KT; ++kt) {
    const int e = kt >> 4;
    const int kc = (kt << 6) & (DIN - 1);
    if ((kt & 15) == 0) {
#pragma unroll
      for (int i = 0; i < 4; ++i)
        gA[i] = gates[(size_t)(bm * 128 + i * 32 + sr) * NE + e];
    }
#pragma unroll
    for (int i = 0; i < 4; ++i) {
      const int r = i * 32 + sr;
      const float* src = x + (size_t)(bm * 128 + r) * DIN + kc + sc;
      float4 a0 = *reinterpret_cast<const float4*>(src);
      float4 a1 = *reinterpret_cast<const float4*>(src + 4);
      const float g = gA[i];
      short8 v;
      v[0] = (short)f2bf(a0.x * g); v[1] = (short)f2bf(a0.y * g);
      v[2] = (short)f2bf(a0.z * g); v[3] = (short)f2bf(a0.w * g);
      v[4] = (short)f2bf(a1.x * g); v[5] = (short)f2bf(a1.y * g);
      v[6] = (short)f2bf(a1.z * g); v[7] = (short)f2bf(a1.w * g);
      *reinterpret_cast<short8*>(&As[r][sc]) = v;
    }
#pragma unroll
    for (int i = 0; i < 4; ++i) {
      const int r = i * 32 + sr;
      const float* src = w + ((size_t)e * DOUT + bn * 128 + r) * DIN + kc + sc;
      float4 a0 = *reinterpret_cast<const float4*>(src);
      float4 a1 = *reinterpret_cast<const float4*>(src + 4);
      short8 v;
      v[0] = (short)f2bf(a0.x); v[1] = (short)f2bf(a0.y);
      v[2] = (short)f2bf(a0.z); v[3] = (short)f2bf(a0.w);
      v[4] = (short)f2bf(a1.x); v[5] = (short)f2bf(a1.y);
      v[6] = (short)f2bf(a1.z); v[7] = (short)f2bf(a1.w);
      *reinterpret_cast<short8*>(&Bs[r][sc]) = v;
    }
    __syncthreads();
#pragma unroll
    for (int kh = 0; kh < 2; ++kh) {
      short8 af[4], bfr[4];
#pragma unroll
      for (int mi = 0; mi < 4; ++mi)
        af[mi] = *reinterpret_cast<const short8*>(&As[wm * 64 + mi * 16 + lr][kh * 32 + lkb]);
#pragma unroll
      for (int ni = 0; ni < 4; ++ni)
        bfr[ni] = *reinterpret_cast<const short8*>(&Bs[wn * 64 + ni * 16 + lr][kh * 32 + lkb]);
#pragma unroll
      for (int mi = 0; mi < 4; ++mi)
#pragma unroll
        for (int ni = 0; ni < 4; ++ni)
          acc[mi][ni] = __builtin_amdgcn_mfma_f32_16x16x32_bf16(
              af[mi], bfr[ni], acc[mi][ni], 0, 0, 0);
    }
    __syncthreads();
  }
  const int orow0 = bm * 128 + wm * 64;
  const int ocol0 = bn * 128 + wn * 64;
  const int rq = (lane >> 4) * 4;
  const int cc = lane & 15;
  float bcol[4][NE];
#pragma unroll
  for (int ni = 0; ni < 4; ++ni) {
    const int col = ocol0 + ni * 16 + cc;
#pragma unroll
    for (int e = 0; e < NE; ++e) bcol[ni][e] = bias[e * DOUT + col];
  }
#pragma unroll
  for (int mi = 0; mi < 4; ++mi) {
#pragma unroll
    for (int q = 0; q < 4; ++q) {
      const int row = orow0 + mi * 16 + rq + q;
      const float4 g0 = *reinterpret_cast<const float4*>(gates + (size_t)row * NE);
      const float4 g1 = *reinterpret_cast<const float4*>(gates + (size_t)row * NE + 4);
#pragma unroll
      for (int ni = 0; ni < 4; ++ni) {
        float s = g0.x * bcol[ni][0] + g0.y * bcol[ni][1]
                + g0.z * bcol[ni][2] + g0.w * bcol[ni][3]
                + g1.x * bcol[ni][4] + g1.y * bcol[ni][5]
                + g1.z * bcol[ni][6] + g1.w * bcol[ni][7];
        out[(size_t)row * DOUT + ocol0 + ni * 16 + cc] = acc[mi][ni][q] + s;
      }
    }
  }
}

extern "C" void kernel_launch(void* const* d_in, const int* in_sizes, int n_in,
                              void* d_out, int out_size, void* d_ws, size_t ws_size,
                              hipStream_t stream) {
  const float* x  = (const float*)d_in[0];
  const float* ew = (const float*)d_in[1];
  const float* eb = (const float*)d_in[2];
  const float* gw = (const float*)d_in[3];
  const float* gb = (const float*)d_in[4];
  float* out = (float*)d_out;

  const size_t G_BYTES  = (size_t)N_TOK * NE * 4;
  const size_t XB_BYTES = (size_t)N_TOK * DIN * 2;
  const size_t WB_BYTES = (size_t)NE * DOUT * DIN * 2;

  if (ws_size >= G_BYTES + XB_BYTES + WB_BYTES) {
    float* gates = (float*)d_ws;
    unsigned short* xb = (unsigned short*)((char*)d_ws + G_BYTES);
    unsigned short* wb = (unsigned short*)((char*)d_ws + G_BYTES + XB_BYTES);

    const int gates_blocks = N_TOK / 4;                         // 2048
    const int cvtw_blocks  = (NE * DOUT * DIN) / (256 * 8);     // 4096
    prep_fused<<<gates_blocks + cvtw_blocks, 256, 0, stream>>>(
        x, ew, gw, gb, gates, xb, wb);
    moe_gemm_v10<<<(N_TOK / BM) * (DOUT / BN), 512, 0, stream>>>(xb, wb, eb, gates, out);
  } else {
    float* gates = (float*)d_ws;
    gates_kernel<<<N_TOK / 4, 256, 0, stream>>>(x, gw, gb, gates);
    dim3 grid(N_TOK / 128, DOUT / 128);
    moe_gemm<<<grid, 256, 0, stream>>>(x, ew, eb, gates, out);
  }
}